// Round 3
// baseline (409.813 us; speedup 1.0000x reference)
//
#include <hip/hip_runtime.h>
#include <hip/hip_bf16.h>

// BlurredNoise via MFMA implicit GEMM, round 11 = round 10 + odd-U areg fix.
// R10 root cause: segment <5,3,4,16,1> has odd U=3, NG=4; areg parity was
// group-local (i&1), so the i=U-1 prefetch of next-group step 0 landed in
// areg[U&1]=areg[1] while next group's i=0 consumed areg[0] -> 3 steps used
// stale A fragments. Fix: step-global parity ap = ((U&1 ? g : 0) + i) & 1;
// for even U this folds to the old i&1 codegen exactly.
// Structure (R10): 4-wave blocks share B via LDS double-buffered chunks,
// reg-staged (load early / ds_write late), one __syncthreads per group.
// Global B traffic /4 vs R9; B reads on the LDS pipe instead of VMEM.
// out[bc][F][t] = scale[F] * sum_j x[bc][t+j] * k[F][j]

#define KS      5000
#define IN_SEQ  9095
#define T_OUT   4096
#define NBC     16
#define NF      128
#define NSTEP   157
#define SWZSTEP 176               // padded per-tile step stride
#define CSTRIDE 1056              // bytes; /4 = 264 == 8 mod 32 -> uniform banks
#define XBUF    (4*CSTRIDE)       // 4224 B per parity buffer
#define XPS     9344              // padded x row stride (floats), front pad 32
#define XTAIL   256               // zero tail: U=2 staging over-reads (unread)
#define SWZ_BYTES (8*SWZSTEP*512*2)   // 1,441,792
#define MT      2                 // m-tiles per wave (32 output t)
#define CHUNK   16384             // B LDS chunk bytes (max W*U = 16 tiles)
#define XREG    (2*XBUF)          // per-wave x LDS region: 8448 B
#define BOFF    (4*XREG)          // 33792: B double-buffer offset in LDS

typedef __attribute__((ext_vector_type(8))) short v8s;
typedef __attribute__((ext_vector_type(4))) float v4f;

__device__ __forceinline__ unsigned short f2b(float v) {
  union { __hip_bfloat16 h; unsigned short u; } cv;
  cv.h = __float2bfloat16(v);   // RNE
  return cv.u;
}

// ---- fused pre-kernel: (a) filters -> B-frag bf16; (b) zero-padded x copy ----
__global__ void build_pre(const float* __restrict__ filt,
                          const float* __restrict__ noise,
                          unsigned short* __restrict__ swz,
                          float* __restrict__ xpad) {
  const int b = blockIdx.x;
  if (b < 314) {                       // swz job: thread -> 8 consecutive shorts
    const int i = b * 256 + threadIdx.x;
    if (i >= 8 * NSTEP * 64) return;
    const int n  = i & 15;
    const int q  = (i >> 4) & 3;
    const int sb = i >> 6;
    const int ft = sb / NSTEP;
    const int s  = sb - ft * NSTEP;
    const int jg0 = KS - 32 * (s + 1) + 8 * q;
    const float* row = filt + (size_t)(ft * 16 + n) * KS;
    unsigned short o[8];
    #pragma unroll
    for (int j = 0; j < 8; ++j) {
      int jg = jg0 + j;
      int jc = jg < 0 ? 0 : jg;          // clamp ADDRESS, select VALUE
      float v = (jg >= 0) ? row[jc] : 0.0f;
      o[j] = f2b(v);
    }
    *(uint4*)(swz + (((size_t)(ft * SWZSTEP + s)) << 9) + (q << 7) + (n << 3)) = *(uint4*)o;
  } else {                             // xpad job: 16 x XPS (+tail), zeros outside
    const int i = (b - 314) * 256 + threadIdx.x;
    if (i >= NBC * XPS + XTAIL) return;
    const int r = i / XPS;
    const int pcol = i - r * XPS;
    const int lg = pcol - 32;
    xpad[i] = (r < NBC && lg >= 0 && lg < IN_SEQ) ? noise[r * IN_SEQ + lg] : 0.0f;
  }
}

// ---- one constant-width segment of the k-loop ----
// W: live tiles (n in [8-W,8)); U: steps/group; NG: groups; SB: first step;
// D: B ds_read prefetch depth (D<=U). B chunks (W*U KB <= 16KB) are staged
// cooperatively by the block's 4 waves: global loads issued at group start,
// LDS writes at group end, one barrier per group (standard double buffer).
template<int W, int U, int NG, int SB, int D>
__device__ __forceinline__ void run_seg(
    const char* __restrict__ swzg, const float* __restrict__ xn,
    char* lds, int xrd_off, int t0, int lane, int wid, v4f (&acc)[MT][8])
{
  constexpr int TILES = W * U;
  constexpr int TPW   = (TILES + 3) / 4;
  constexpr int LOADI = (U >= 3) ? 2 : 1;
  constexpr int ODD   = U & 1;          // odd-U: areg parity must be step-global

  char* xw  = lds + wid * XREG;        // per-wave x region (may-alias lds)
  char* bB  = lds + BOFF;              // shared B double buffer
  const char* xrd = xw + xrd_off;

  v8s breg[D][W];
  v8s areg[2][MT];
  float4 xr[3];
  uint4 bstg[TPW];

  // -- B chunk staging (cooperative, reg-staged, issue-early/write-late) --
  auto loadB = [&](int g) {
    #pragma unroll
    for (int j = 0; j < TPW; ++j) {
      const int tile = wid * TPW + j;
      if (tile < TILES) {
        const int wp = tile / U;
        const int u  = tile - wp * U;
        const int s  = SB + g * U + u;
        bstg[j] = *(const uint4*)(swzg +
            (((size_t)((8 - W + wp) * SWZSTEP + s)) << 10) + 16 * lane);
      }
    }
  };
  auto writeB = [&](int par) {
    #pragma unroll
    for (int j = 0; j < TPW; ++j) {
      const int tile = wid * TPW + j;
      if (tile < TILES)
        *(uint4*)(bB + par * CHUNK + (tile << 10) + 16 * lane) = bstg[j];
    }
  };
  auto readB = [&](int par, int w, int step) -> v8s {
    return *(const v8s*)(bB + par * CHUNK + ((w * U + step) << 10) + 16 * lane);
  };

  // -- per-wave x staging machinery (unchanged from r8/r9) --
  auto stage_load = [&](int gg) {      // unconditional, aligned (padded buffer)
    const int g0 = t0 + KS - 32 * (SB + (gg + 1) * U);
    #pragma unroll
    for (int ii = 0; ii < 3; ++ii)
      xr[ii] = *(const float4*)(xn + (g0 + 8 * lane + 4 * ii));
  };
  auto stage_write = [&](int parity) { // xr -> 4 shifted bf16 LDS copies
    const float* f = (const float*)xr;
    unsigned u6[6];
    #pragma unroll
    for (int j = 0; j < 6; ++j)
      u6[j] = (unsigned)f2b(f[2 * j]) | ((unsigned)f2b(f[2 * j + 1]) << 16);
    auto AL = [](unsigned hi, unsigned lo) { return (lo >> 16) | (hi << 16); };
    char* buf = xw + parity * XBUF + 16 * lane;
    uint4 w0 = {u6[0], u6[1], u6[2], u6[3]};
    uint4 w1 = {AL(u6[1],u6[0]), AL(u6[2],u6[1]), AL(u6[3],u6[2]), AL(u6[4],u6[3])};
    uint4 w2 = {u6[1], u6[2], u6[3], u6[4]};
    uint4 w3 = {AL(u6[2],u6[1]), AL(u6[3],u6[2]), AL(u6[4],u6[3]), AL(u6[5],u6[4])};
    *(uint4*)(buf + 0 * CSTRIDE) = w0;
    *(uint4*)(buf + 1 * CSTRIDE) = w1;
    *(uint4*)(buf + 2 * CSTRIDE) = w2;
    *(uint4*)(buf + 3 * CSTRIDE) = w3;
  };
  auto read_A = [&](const char* p, v8s (&dst)[MT]) {
    #pragma unroll
    for (int mt = 0; mt < MT; ++mt) {
      v8s a;
      *(uint2*)&a       = *(const uint2*)(p + 32 * mt);
      *((uint2*)&a + 1) = *(const uint2*)(p + 32 * mt + 8);
      dst[mt] = a;
    }
  };

  // segment prologue: B chunk0 load (first, so writeB's vmcnt wait skips x),
  // x group0 staged + group1 loaded, chunk0 written, barrier, A step SB.
  loadB(0);
  stage_load(0);
  stage_write(0);
  stage_load(NG > 1 ? 1 : 0);
  writeB(0);
  __syncthreads();
  read_A(xrd + 64 * (U - 1), areg[0]);

  #pragma unroll 1
  for (int g = 0; g < NG; ++g) {
    if (g + 1 < NG) loadB(g + 1);      // issue next chunk's global loads early
    #pragma unroll
    for (int d = 0; d < D; ++d)        // B prologue from current LDS chunk
      #pragma unroll
      for (int w = 0; w < W; ++w)
        breg[d][w] = readB(g & 1, w, d);
    #pragma unroll
    for (int i = 0; i < U; ++i) {
      const int ap = ((ODD ? g : 0) + i) & 1;   // step-global A parity
      if (i == 1) stage_write((g + 1) & 1);   // garbage parity-write if g+1==NG (unread)
      if (i == LOADI) { int gg = g + 2; gg = gg > NG - 1 ? NG - 1 : gg; stage_load(gg); }
      // A prefetch for next step
      {
        const char* pn;
        if (i + 1 < U) {
          pn = xrd + (g & 1) * XBUF + 64 * (U - 2 - i);
        } else {
          int gn = (g + 1 < NG) ? (g + 1) : g;
          pn = xrd + (gn & 1) * XBUF + 64 * (U - 1);
        }
        read_A(pn, areg[ap ^ 1]);
      }
      // MFMA: use B slot i%D (read D steps ago), then refill same slot
      #pragma unroll
      for (int w = 0; w < W; ++w)
        #pragma unroll
        for (int mt = 0; mt < MT; ++mt)
          acc[mt][8 - W + w] = __builtin_amdgcn_mfma_f32_16x16x32_bf16(
              areg[ap][mt], breg[i % D][w], acc[mt][8 - W + w], 0, 0, 0);
      if (i + D < U) {
        #pragma unroll
        for (int w = 0; w < W; ++w)
          breg[i % D][w] = readB(g & 1, w, i + D);
      }
    }
    if (g + 1 < NG) writeB((g + 1) & 1);   // next chunk -> LDS before barrier
    __syncthreads();                        // chunk swap; also guards next segment
  }
}

// ---- main kernel: 512 blocks x 256 threads (4 waves share B via LDS) ----
__global__ __launch_bounds__(256, 2) void blur_mfma(
    const float* __restrict__ xpad,
    const unsigned short* __restrict__ swz,
    const float* __restrict__ scale,
    float* __restrict__ out)
{
  __shared__ __align__(16) char lds[BOFF + 2 * CHUNK];   // 66,560 B -> 2 blk/CU
  const int tid  = threadIdx.x;
  const int lane = tid & 63;
  const int wid  = tid >> 6;
  const int b  = blockIdx.x;
  const int bc = b >> 5;                    // 16 bc x 32 t-chunks of 128
  const int t0 = ((b & 31) << 7) + (wid << 5);  // 32 output t per wave
  const int m = lane & 15, q = lane >> 4, c = m & 3;
  const float* __restrict__ xn = xpad + (size_t)bc * XPS + 32;  // logical origin
  const char* swzg = (const char*)swz;
  const int xrd_off = c * CSTRIDE + 8 * (m >> 2) + 16 * q;

  v4f acc[MT][8];
  const v4f vz = {0.f, 0.f, 0.f, 0.f};
  #pragma unroll
  for (int mt = 0; mt < MT; ++mt)
    #pragma unroll
    for (int n = 0; n < 8; ++n) acc[mt][n] = vz;

  // segments: <W, U, NG, SB, D>; step spans {8,4,4,12,12,24,36,48,9} = 157
  run_seg<8,  2, 4,   0, 1>(swzg, xn, lds, xrd_off, t0, lane, wid, acc);
  run_seg<7,  2, 2,   8, 1>(swzg, xn, lds, xrd_off, t0, lane, wid, acc);
  run_seg<6,  2, 2,  12, 1>(swzg, xn, lds, xrd_off, t0, lane, wid, acc);
  run_seg<5,  3, 4,  16, 1>(swzg, xn, lds, xrd_off, t0, lane, wid, acc);
  run_seg<4,  4, 3,  28, 1>(swzg, xn, lds, xrd_off, t0, lane, wid, acc);
  run_seg<3,  4, 6,  40, 2>(swzg, xn, lds, xrd_off, t0, lane, wid, acc);
  run_seg<2,  6, 6,  64, 2>(swzg, xn, lds, xrd_off, t0, lane, wid, acc);
  run_seg<1, 12, 4, 100, 4>(swzg, xn, lds, xrd_off, t0, lane, wid, acc);
  run_seg<1,  9, 1, 148, 3>(swzg, xn, lds, xrd_off, t0, lane, wid, acc);

  // epilogue: D col=lane&15 -> filter-in-tile, row=4q+reg -> t offset
  #pragma unroll
  for (int n = 0; n < 8; ++n) {
    const int F = 16 * n + m;
    const float sc = scale[F];
    #pragma unroll
    for (int mt = 0; mt < MT; ++mt) {
      v4f o = acc[mt][n] * sc;
      *(v4f*)(out + (size_t)(bc * NF + F) * T_OUT + t0 + 16 * mt + 4 * q) = o;
    }
  }
}

extern "C" void kernel_launch(void* const* d_in, const int* in_sizes, int n_in,
                              void* d_out, int out_size, void* d_ws, size_t ws_size,
                              hipStream_t stream) {
  const float* noise = (const float*)d_in[0];   // (2, 8, 9095) fp32
  const float* filt  = (const float*)d_in[1];   // (128, 5000) fp32
  const float* scale = (const float*)d_in[2];   // (1, 128, 1) fp32
  float* out = (float*)d_out;                   // (2, 1024, 4096) fp32

  unsigned short* swz = (unsigned short*)d_ws;              // 1.44 MB
  float* xpad = (float*)((char*)d_ws + SWZ_BYTES);          // 16 x 9344 fp32 + tail

  const int pad_blocks = (NBC * XPS + XTAIL + 255) / 256;   // 585
  build_pre<<<314 + pad_blocks, 256, 0, stream>>>(filt, noise, swz, xpad);
  blur_mfma<<<512, 256, 0, stream>>>(xpad, swz, scale, out);
}